// Round 9
// baseline (140.922 us; speedup 1.0000x reference)
//
#include <hip/hip_runtime.h>

// Conv2D 3x3 stride-1 pad-1, C_IN=C_OUT=16, H=W=1024, fp32 in/out.
// Fused implicit-GEMM. v9: rolling row-ring, fine-grained phases, 4 blk/CU.
//  - Scoreboard: coarse-phase barrier blocks = 39-52us; barrier-free 1-wave
//    blocks = 57-75us (residency-starved). Common defect: monolithic
//    stage/compute phases -> 2 coarse streams/CU, bursty reads.
//  - v9: block = 64 cols x 16 output rows, iterating 4-row steps with a
//    16-row-slot LDS ring (16*66 px * 32B = 33792B -> 4 blocks/CU; grid
//    16x64 = 1024 = exactly 4/CU, 16 waves/CU). Per iter: compute(4 rows);
//    issue loads group g+3 (3 AHEAD); write group g+2; lgkm-only barrier.
//    Short phases x 4 staggered blocks = near-continuous read demand.
//  - Ring slot = input-row-index mod 16. Intra-iter write/compute are
//    slot-disjoint for every g (write idx 4g+8..4g+11 vs read 4g..4g+5),
//    so only cross-barrier ordering matters; barrier = lgkmcnt(0)-only +
//    s_barrier (r5-validated; global stores NEVER drained).
//  - Vertical halo inside the block eliminated by the ring (rows staged
//    once); only 2/16 boundary rows re-read across blocks + 2/64 cols.
//  - Staging: 256 body px-tasks (lane = one px, 16 channel-strided scalar
//    loads; lanes cover 64 consecutive px -> 256B dense segments/instr)
//    + 8 halo px-tasks (tid<8, single buffer, loaded 1 iter ahead).
//    v_cvt_pk_bf16_f32 pack, 2x ds_write_b128 per px, XOR chunk swizzle.
//  - Weights: r8-validated per-lane register gather (L2-hot 9KB) -> a[5].
//  - Compute: wave w owns row 4g+w: 4 colgroups x 5 mfma_f32_16x16x32_bf16.

#define HH 1024
#define WW 1024
#define CIN 16
#define HWP (HH * WW)
#define TW 64
#define CH 16                  // output rows per block
#define LCOLS 66
#define RS 16                  // ring slots (rows)
#define CPR (LCOLS * 2)        // chunks per row-slot = 132

typedef short v8s __attribute__((ext_vector_type(8)));
typedef float v4f __attribute__((ext_vector_type(4)));
typedef unsigned int u32;

// packed {bf16(hi)<<16 | bf16(lo)}, hardware RNE
__device__ __forceinline__ u32 cvt_pk_bf16(float lo, float hi) {
    u32 r;
    asm("v_cvt_pk_bf16_f32 %0, %1, %2" : "=v"(r) : "v"(lo), "v"(hi));
    return r;
}

__device__ __forceinline__ int swz(int c) { return c ^ ((c >> 3) & 7); }

// Workgroup barrier WITHOUT the vmcnt(0) store/load drain __syncthreads adds.
__device__ __forceinline__ void wave_barrier() {
    __builtin_amdgcn_sched_barrier(0);
    asm volatile("s_waitcnt lgkmcnt(0)" ::: "memory");
    __builtin_amdgcn_sched_barrier(0);
    __builtin_amdgcn_s_barrier();
    __builtin_amdgcn_sched_barrier(0);
}

__global__ __launch_bounds__(256, 4)
void conv3x3_ring(const float* __restrict__ x,
                  const float* __restrict__ wgt,
                  const float* __restrict__ bias,
                  float* __restrict__ out) {
    __shared__ __align__(16) unsigned short sm[RS * LCOLS * 16];  // 33792 B

    const int tid = threadIdx.x;
    const int lane = tid & 63;
    const int wave = tid >> 6;
    const int m = lane & 15;       // c_out row of A == pixel col of B/D
    const int q = lane >> 4;       // k-quad: supplies k = 8q..8q+7
    const int w0 = blockIdx.x * TW;
    const int h0 = blockIdx.y * CH;

    // ---- weight fragments in registers (gather from hot 9KB, L2-res) ----
    // a[g5] elem j = W[m][(t&1)*8+j][kh][kw], t = 4*g5+q, kh*3+kw = t>>1.
    v8s a[5];
    #pragma unroll
    for (int g5 = 0; g5 < 5; ++g5) {
        const int t = 4 * g5 + q;
        union { u32 u[4]; v8s v; } wv;
        if (t < 18) {
            const int base = m * 144 + (t & 1) * 72 + (t >> 1);
            #pragma unroll
            for (int jj = 0; jj < 4; ++jj) {
                const float lo = wgt[base + 18 * jj];      // j = 2jj
                const float hi = wgt[base + 18 * jj + 9];  // j = 2jj+1
                wv.u[jj] = cvt_pk_bf16(lo, hi);
            }
        } else {
            wv.u[0] = wv.u[1] = wv.u[2] = wv.u[3] = 0u;
        }
        a[g5] = wv.v;
    }
    float bl[4];
    #pragma unroll
    for (int i = 0; i < 4; ++i) bl[i] = bias[q * 4 + i];

    // ---- per-lane tap decomposition: t = 4g+q -> kh (slot calc) + chunk
    //      offset within a row-slot: (m+kw)*2 + half ----
    int Koff[5], kh5[5];
    #pragma unroll
    for (int g5 = 0; g5 < 5; ++g5) {
        int t = 4 * g5 + q;
        int tt = t > 17 ? 17 : t;      // dead lanes use a harmless valid addr
        int khkw = tt >> 1;
        int kh = khkw / 3;
        int kw = khkw - 3 * kh;
        kh5[g5] = kh;
        Koff[g5] = (m + kw) * 2 + (tt & 1);
    }

    // ---- staging. group G covers input rows idx 4G..4G+3 (idx rel h0-1);
    //      G=0..3 full (4 rows), G=4 partial (2 rows: idx 16,17).
    //      body: task tid -> rr = tid>>6 (row in group), col cc = (tid&63)+1
    //      halo: tid<2*nr -> rr = tid>>1, col 0 or 65 ----
    auto loadB = [&](int G, float* f) {
        const int nr = (G == 4) ? 2 : 4;
        const int rr = tid >> 6;
        if (rr < nr) {
            const int gh = h0 - 1 + 4 * G + rr;
            const int gw = w0 + (tid & 63);            // cols 1..64 -> in-range
            if ((unsigned)gh < (unsigned)HH) {
                const float* p = x + (size_t)gh * WW + gw;
                #pragma unroll
                for (int c = 0; c < CIN; ++c) f[c] = p[(size_t)c * HWP];
            } else {
                #pragma unroll
                for (int c = 0; c < CIN; ++c) f[c] = 0.f;
            }
        }
    };
    auto writeB = [&](int G, const float* f) {
        const int nr = (G == 4) ? 2 : 4;
        const int rr = tid >> 6;
        if (rr < nr) {
            const int slot = (4 * G + rr) & (RS - 1);
            const int p = slot * LCOLS + (tid & 63) + 1;
            u32 pk[8];
            #pragma unroll
            for (int i = 0; i < 8; ++i)
                pk[i] = cvt_pk_bf16(f[2 * i], f[2 * i + 1]);
            *(uint4*)(sm + swz(2 * p) * 8)     = *(uint4*)&pk[0];
            *(uint4*)(sm + swz(2 * p + 1) * 8) = *(uint4*)&pk[4];
        }
    };
    auto loadH = [&](int G, float* f) {
        const int nh = (G == 4) ? 4 : 8;
        if (tid < nh) {
            const int gh = h0 - 1 + 4 * G + (tid >> 1);
            const int gw = (tid & 1) ? (w0 + TW) : (w0 - 1);
            if ((unsigned)gh < (unsigned)HH && (unsigned)gw < (unsigned)WW) {
                const float* p = x + (size_t)gh * WW + gw;
                #pragma unroll
                for (int c = 0; c < CIN; ++c) f[c] = p[(size_t)c * HWP];
            } else {
                #pragma unroll
                for (int c = 0; c < CIN; ++c) f[c] = 0.f;
            }
        }
    };
    auto writeH = [&](int G, const float* f) {
        const int nh = (G == 4) ? 4 : 8;
        if (tid < nh) {
            const int slot = (4 * G + (tid >> 1)) & (RS - 1);
            const int p = slot * LCOLS + ((tid & 1) ? 65 : 0);
            u32 pk[8];
            #pragma unroll
            for (int i = 0; i < 8; ++i)
                pk[i] = cvt_pk_bf16(f[2 * i], f[2 * i + 1]);
            *(uint4*)(sm + swz(2 * p) * 8)     = *(uint4*)&pk[0];
            *(uint4*)(sm + swz(2 * p + 1) * 8) = *(uint4*)&pk[4];
        }
    };

    // ---- compute iteration g: wave w -> output row h0 + 4g + w ----
    auto compute = [&](int g) {
        const int R = h0 + 4 * g + wave;
        #pragma unroll
        for (int cg = 0; cg < 4; ++cg) {
            v4f acc = {0.f, 0.f, 0.f, 0.f};
            #pragma unroll
            for (int g5 = 0; g5 < 5; ++g5) {
                const int slot = (4 * g + wave + kh5[g5]) & (RS - 1);
                const int c = slot * CPR + cg * 32 + Koff[g5];
                v8s b = *(const v8s*)(sm + swz(c) * 8);
                acc = __builtin_amdgcn_mfma_f32_16x16x32_bf16(a[g5], b, acc, 0, 0, 0);
            }
            float* op = out + (size_t)R * WW + (w0 + cg * 16 + m);
            #pragma unroll
            for (int i = 0; i < 4; ++i)
                op[(size_t)(q * 4 + i) * HWP] = acc[i] + bl[i];
        }
        __builtin_amdgcn_sched_barrier(0);
    };

    // ---- prologue: stage G0,G1; issue G2 across the barrier ----
    float f0[CIN], f1[CIN], fh[CIN];
    loadB(0, f0);
    loadB(1, f1);
    loadH(0, fh);
    writeB(0, f0);
    writeH(0, fh);
    loadH(1, fh);                      // fh consumed by writeH(0) above
    writeB(1, f1);
    writeH(1, fh);
    loadB(2, f0);                      // f0 freed by writeB(0)
    loadH(2, fh);                      // fh freed by writeH(1)
    __builtin_amdgcn_sched_barrier(0);
    wave_barrier();

    // ---- iter 0: compute rows 0..3; write G2; issue G3 ----
    compute(0);
    loadB(3, f1);                      // f1 freed by writeB(1)
    writeB(2, f0);
    writeH(2, fh);
    loadH(3, fh);
    wave_barrier();

    // ---- iter 1: compute rows 4..7; write G3; issue G4 ----
    compute(1);
    loadB(4, f0);                      // f0 freed by writeB(2)
    writeB(3, f1);
    writeH(3, fh);
    loadH(4, fh);
    wave_barrier();

    // ---- iter 2: compute rows 8..11; write G4 (partial: idx 16,17) ----
    compute(2);
    writeB(4, f0);
    writeH(4, fh);
    wave_barrier();

    // ---- iter 3: compute rows 12..15 (uses slots of idx 12..17) ----
    compute(3);
}

extern "C" void kernel_launch(void* const* d_in, const int* in_sizes, int n_in,
                              void* d_out, int out_size, void* d_ws, size_t ws_size,
                              hipStream_t stream) {
    const float* x = (const float*)d_in[0];
    const float* w = (const float*)d_in[1];
    const float* b = (const float*)d_in[2];
    float* out = (float*)d_out;
    dim3 grid(WW / TW, HH / CH);
    conv3x3_ring<<<grid, dim3(256), 0, stream>>>(x, w, b, out);
}